// Round 1
// baseline (43.178 us; speedup 1.0000x reference)
//
#include <hip/hip_runtime.h>

#define BATCH   512
#define NPRED   1176
#define NTGT    64
#define PRED_C  9
#define THREADS 256
#define CHUNK   (NPRED / 4)   // 294 preds per wave

__global__ __launch_bounds__(THREADS) void det_loss_main(
    const float* __restrict__ pred,   // (B, N, 9)
    const float* __restrict__ tbox,   // (B, T, 4)
    const int*   __restrict__ tcls,   // (B, T)
    float* __restrict__ partial)      // (B,)
{
    __shared__ float4 sbox[NPRED];    // decoded boxes
    __shared__ float  sarea[NPRED];   // w*h
    __shared__ float  slogit[NPRED];  // conf logits
    __shared__ float  spos[NPRED];    // matched mask
    __shared__ float4 stgt[NTGT];
    __shared__ float  sbiou[THREADS];
    __shared__ int    sbidx[THREADS];
    __shared__ float  sred[4];

    const int b   = blockIdx.x;
    const int tid = threadIdx.x;
    const float* pb = pred + (size_t)b * NPRED * PRED_C;

    // ---- Phase A: decode boxes -> LDS, accumulate logaddexp(0, conf) ----
    float s_conf = 0.f;
    for (int n = tid; n < NPRED; n += THREADS) {
        const float* p = pb + n * PRED_C;
        float p0 = p[0], p1 = p[1], p2 = p[2], p3 = p[3], p4 = p[4];
        float cx = (p0 * 2.f - 1.f) * 736.f;   // IMG_W/2
        float cy = (p1 * 2.f - 1.f) * 416.f;   // IMG_H/2
        float w  = expf(p2) * 32.f;            // 1472/46 == 32 exactly
        float h  = expf(p3) * 32.f;            // 832/26  == 32 exactly
        sbox[n]   = make_float4(cx - 0.5f * w, cy - 0.5f * h,
                                cx + 0.5f * w, cy + 0.5f * h);
        sarea[n]  = w * h;
        slogit[n] = p4;
        spos[n]   = 0.f;
        // logaddexp(0, x) = max(x,0) + log1p(exp(-|x|))
        s_conf += fmaxf(p4, 0.f) + log1pf(expf(-fabsf(p4)));
    }
    if (tid < NTGT) {
        stgt[tid] = *reinterpret_cast<const float4*>(
            tbox + ((size_t)b * NTGT + tid) * 4);
    }
    __syncthreads();

    // ---- Phase B: per-target argmax of IoU over N (wave w owns n-chunk w) ----
    {
        int w = tid >> 6, t = tid & 63;
        float4 tb = stgt[t];
        float a2 = (tb.z - tb.x) * (tb.w - tb.y);
        float bi = -1.f; int bn = 0;
        int n0 = w * CHUNK;
        for (int n = n0; n < n0 + CHUNK; ++n) {
            float4 bb = sbox[n];                 // LDS broadcast across lanes
            float ix1 = fmaxf(bb.x, tb.x);
            float iy1 = fmaxf(bb.y, tb.y);
            float ix2 = fminf(bb.z, tb.z);
            float iy2 = fminf(bb.w, tb.w);
            float iw  = fmaxf(ix2 - ix1, 0.f);
            float ih  = fmaxf(iy2 - iy1, 0.f);
            float inter = iw * ih;
            float uni   = sarea[n] + a2 - inter; // > 0 always (areas > 0)
            float iou   = inter / uni;
            if (iou > bi) { bi = iou; bn = n; }  // strict > keeps first index
        }
        sbiou[tid] = bi; sbidx[tid] = bn;
    }
    __syncthreads();

    // ---- Phase C (lanes 0..63): combine waves, box + cls loss, pos mask ----
    float s_box = 0.f, s_cls = 0.f;
    if (tid < NTGT) {
        float bi = sbiou[tid]; int bn = sbidx[tid];
        for (int w = 1; w < 4; ++w) {            // ascending order: first-max wins
            float v = sbiou[w * 64 + tid];
            if (v > bi) { bi = v; bn = sbidx[w * 64 + tid]; }
        }
        int m = bn;
        spos[m] = 1.f;                           // set semantics; dup writes benign

        float4 pbx = sbox[m];
        float4 tb  = stgt[tid];
        float d;
        d = fabsf(pbx.x - tb.x); s_box += (d < 1.f) ? 0.5f * d * d : d - 0.5f;
        d = fabsf(pbx.y - tb.y); s_box += (d < 1.f) ? 0.5f * d * d : d - 0.5f;
        d = fabsf(pbx.z - tb.z); s_box += (d < 1.f) ? 0.5f * d * d : d - 0.5f;
        d = fabsf(pbx.w - tb.w); s_box += (d < 1.f) ? 0.5f * d * d : d - 0.5f;

        const float* pc = pb + m * PRED_C + 5;
        float x0 = pc[0], x1 = pc[1], x2 = pc[2], x3 = pc[3];
        float mx = fmaxf(fmaxf(x0, x1), fmaxf(x2, x3));
        float se = expf(x0 - mx) + expf(x1 - mx) + expf(x2 - mx) + expf(x3 - mx);
        float lse = mx + logf(se);
        int tc = tcls[(size_t)b * NTGT + tid];
        float xt = (tc == 0) ? x0 : (tc == 1) ? x1 : (tc == 2) ? x2 : x3;
        s_cls += lse - xt;
    }
    __syncthreads();

    // ---- Phase D: subtract matched conf logits (deduped via mask) ----
    float s_pos = 0.f;
    for (int n = tid; n < NPRED; n += THREADS)
        s_pos += spos[n] * slogit[n];

    // ---- block reduction of 5*box + cls + conf ----
    float v = s_conf - s_pos + 5.f * s_box + s_cls;
    for (int off = 32; off > 0; off >>= 1)
        v += __shfl_down(v, off);
    if ((tid & 63) == 0) sred[tid >> 6] = v;
    __syncthreads();
    if (tid == 0)
        partial[b] = sred[0] + sred[1] + sred[2] + sred[3];
}

__global__ __launch_bounds__(BATCH) void det_loss_final(
    const float* __restrict__ partial, float* __restrict__ out)
{
    int tid = threadIdx.x;
    float v = partial[tid];
    for (int off = 32; off > 0; off >>= 1)
        v += __shfl_down(v, off);
    __shared__ float s[8];
    if ((tid & 63) == 0) s[tid >> 6] = v;
    __syncthreads();
    if (tid == 0) {
        float t = 0.f;
        for (int i = 0; i < 8; ++i) t += s[i];
        *out = t * (1.f / BATCH);
    }
}

extern "C" void kernel_launch(void* const* d_in, const int* in_sizes, int n_in,
                              void* d_out, int out_size, void* d_ws, size_t ws_size,
                              hipStream_t stream) {
    const float* pred = (const float*)d_in[0];
    const float* tbox = (const float*)d_in[1];
    const int*   tcls = (const int*)d_in[2];
    float* out     = (float*)d_out;
    float* partial = (float*)d_ws;   // 512 floats, written every call

    det_loss_main<<<BATCH, THREADS, 0, stream>>>(pred, tbox, tcls, partial);
    det_loss_final<<<1, BATCH, 0, stream>>>(partial, out);
}

// Round 2
// 30.786 us; speedup vs baseline: 1.4025x; 1.4025x over previous
//
#include <hip/hip_runtime.h>

#define BATCH   512
#define NPRED   1176
#define NTGT    64
#define PRED_C  9
#define THREADS 512
#define NWAVE   (THREADS / 64)        // 8 waves
#define CHUNK   (NPRED / NWAVE)       // 147 preds per wave

__global__ __launch_bounds__(THREADS) void det_loss_main(
    const float* __restrict__ pred,   // (B, N, 9)
    const float* __restrict__ tbox,   // (B, T, 4)
    const int*   __restrict__ tcls,   // (B, T)
    float* __restrict__ partial)      // (B,)
{
    __shared__ float4 sbox[NPRED];    // decoded boxes
    __shared__ float  sarea[NPRED];   // w*h
    __shared__ float  slogit[NPRED];  // conf logits
    __shared__ float  spos[NPRED];    // matched mask
    __shared__ float4 stgt[NTGT];
    __shared__ float  sbint[THREADS]; // per-wave best inter
    __shared__ float  sbuni[THREADS]; // per-wave best union
    __shared__ int    sbidx[THREADS];
    __shared__ float  sred[NWAVE];

    const int b   = blockIdx.x;
    const int tid = threadIdx.x;
    const float* pb = pred + (size_t)b * NPRED * PRED_C;

    // ---- Phase A: decode boxes -> LDS, accumulate logaddexp(0, conf) ----
    float s_conf = 0.f;
    for (int n = tid; n < NPRED; n += THREADS) {
        const float* p = pb + n * PRED_C;
        float p0 = p[0], p1 = p[1], p2 = p[2], p3 = p[3], p4 = p[4];
        float cx = (p0 * 2.f - 1.f) * 736.f;   // IMG_W/2
        float cy = (p1 * 2.f - 1.f) * 416.f;   // IMG_H/2
        float w  = expf(p2) * 32.f;            // 1472/46 == 32 exactly
        float h  = expf(p3) * 32.f;            // 832/26  == 32 exactly
        sbox[n]   = make_float4(cx - 0.5f * w, cy - 0.5f * h,
                                cx + 0.5f * w, cy + 0.5f * h);
        sarea[n]  = w * h;
        slogit[n] = p4;
        spos[n]   = 0.f;
        // logaddexp(0, x) = max(x,0) + log1p(exp(-|x|))
        s_conf += fmaxf(p4, 0.f) + log1pf(expf(-fabsf(p4)));
    }
    if (tid < NTGT) {
        stgt[tid] = *reinterpret_cast<const float4*>(
            tbox + ((size_t)b * NTGT + tid) * 4);
    }
    __syncthreads();

    // ---- Phase B: per-target argmax of IoU over N, division-free ----
    // candidate n beats best iff inter_n * buni > binter * uni_n  (uni > 0)
    {
        int w = tid >> 6, t = tid & 63;
        float4 tb = stgt[t];
        float a2 = (tb.z - tb.x) * (tb.w - tb.y);
        int   n0 = w * CHUNK;
        float binter = 0.f, buni = 1.f;
        int   bn = n0;
        for (int n = n0; n < n0 + CHUNK; ++n) {
            float4 bb = sbox[n];                 // LDS broadcast across lanes
            float a1  = sarea[n];
            float ix1 = fmaxf(bb.x, tb.x);
            float iy1 = fmaxf(bb.y, tb.y);
            float ix2 = fminf(bb.z, tb.z);
            float iy2 = fminf(bb.w, tb.w);
            float iw  = fmaxf(ix2 - ix1, 0.f);
            float ih  = fmaxf(iy2 - iy1, 0.f);
            float inter = iw * ih;
            float uni   = (a1 + a2) - inter;
            bool better = inter * buni > binter * uni;  // strict: first-max wins
            binter = better ? inter : binter;
            buni   = better ? uni   : buni;
            bn     = better ? n     : bn;
        }
        sbint[tid] = binter; sbuni[tid] = buni; sbidx[tid] = bn;
    }
    __syncthreads();

    // ---- Phase C (lanes 0..63): combine waves, box + cls loss, pos mask ----
    float s_box = 0.f, s_cls = 0.f;
    if (tid < NTGT) {
        float binter = sbint[tid], buni = sbuni[tid];
        int   bn = sbidx[tid];
        for (int w = 1; w < NWAVE; ++w) {        // ascending: first-max wins
            float ci = sbint[w * 64 + tid];
            float cu = sbuni[w * 64 + tid];
            bool better = ci * buni > binter * cu;
            binter = better ? ci : binter;
            buni   = better ? cu : buni;
            bn     = better ? sbidx[w * 64 + tid] : bn;
        }
        int m = bn;
        spos[m] = 1.f;                           // set semantics; dup writes benign

        float4 pbx = sbox[m];
        float4 tb  = stgt[tid];
        float d;
        d = fabsf(pbx.x - tb.x); s_box += (d < 1.f) ? 0.5f * d * d : d - 0.5f;
        d = fabsf(pbx.y - tb.y); s_box += (d < 1.f) ? 0.5f * d * d : d - 0.5f;
        d = fabsf(pbx.z - tb.z); s_box += (d < 1.f) ? 0.5f * d * d : d - 0.5f;
        d = fabsf(pbx.w - tb.w); s_box += (d < 1.f) ? 0.5f * d * d : d - 0.5f;

        const float* pc = pb + m * PRED_C + 5;
        float x0 = pc[0], x1 = pc[1], x2 = pc[2], x3 = pc[3];
        float mx = fmaxf(fmaxf(x0, x1), fmaxf(x2, x3));
        float se = expf(x0 - mx) + expf(x1 - mx) + expf(x2 - mx) + expf(x3 - mx);
        float lse = mx + logf(se);
        int tc = tcls[(size_t)b * NTGT + tid];
        float xt = (tc == 0) ? x0 : (tc == 1) ? x1 : (tc == 2) ? x2 : x3;
        s_cls += lse - xt;
    }
    __syncthreads();

    // ---- Phase D: subtract matched conf logits (deduped via mask) ----
    float s_pos = 0.f;
    for (int n = tid; n < NPRED; n += THREADS)
        s_pos += spos[n] * slogit[n];

    // ---- block reduction of 5*box + cls + conf ----
    float v = s_conf - s_pos + 5.f * s_box + s_cls;
    for (int off = 32; off > 0; off >>= 1)
        v += __shfl_down(v, off);
    if ((tid & 63) == 0) sred[tid >> 6] = v;
    __syncthreads();
    if (tid == 0) {
        float t = 0.f;
        for (int i = 0; i < NWAVE; ++i) t += sred[i];
        partial[b] = t;
    }
}

__global__ __launch_bounds__(BATCH) void det_loss_final(
    const float* __restrict__ partial, float* __restrict__ out)
{
    int tid = threadIdx.x;
    float v = partial[tid];
    for (int off = 32; off > 0; off >>= 1)
        v += __shfl_down(v, off);
    __shared__ float s[8];
    if ((tid & 63) == 0) s[tid >> 6] = v;
    __syncthreads();
    if (tid == 0) {
        float t = 0.f;
        for (int i = 0; i < 8; ++i) t += s[i];
        *out = t * (1.f / BATCH);
    }
}

extern "C" void kernel_launch(void* const* d_in, const int* in_sizes, int n_in,
                              void* d_out, int out_size, void* d_ws, size_t ws_size,
                              hipStream_t stream) {
    const float* pred = (const float*)d_in[0];
    const float* tbox = (const float*)d_in[1];
    const int*   tcls = (const int*)d_in[2];
    float* out     = (float*)d_out;
    float* partial = (float*)d_ws;   // 512 floats, written every call

    det_loss_main<<<BATCH, THREADS, 0, stream>>>(pred, tbox, tcls, partial);
    det_loss_final<<<1, BATCH, 0, stream>>>(partial, out);
}

// Round 3
// 15.044 us; speedup vs baseline: 2.8702x; 2.0464x over previous
//
#include <hip/hip_runtime.h>

#define BATCH   512
#define NPRED   1176
#define NTGT    64
#define PRED_C  9
#define THREADS 512
#define NWAVE   (THREADS / 64)        // 8 waves

__global__ __launch_bounds__(THREADS) void det_loss_main(
    const float* __restrict__ pred,   // (B, N, 9)
    const float* __restrict__ tbox,   // (B, T, 4)
    const int*   __restrict__ tcls,   // (B, T)
    float* __restrict__ partial)      // (B,)
{
    __shared__ float4 sbox[NPRED];    // all decoded boxes (full, for Phase C)
    __shared__ float  slogit[NPRED];  // conf logits
    __shared__ float  spos[NPRED];    // matched mask
    __shared__ float4 stgt[NTGT];
    __shared__ float4 cbox[NPRED];    // compacted candidate boxes
    __shared__ float  carea[NPRED];
    __shared__ int    cidx[NPRED];    // original indices (ascending)
    __shared__ float  shull[4];       // hx1, hy1, hx2, hy2
    __shared__ int    swofs[NWAVE];
    __shared__ int    stotal;
    __shared__ float  sbint[THREADS];
    __shared__ float  sbuni[THREADS];
    __shared__ int    sbidx[THREADS];
    __shared__ float  sred[NWAVE];

    const int b   = blockIdx.x;
    const int tid = threadIdx.x;
    const float* pb = pred + (size_t)b * NPRED * PRED_C;

    // ---- Phase A: decode boxes -> LDS, logaddexp(0, conf); targets + hull ----
    float s_conf = 0.f;
    for (int n = tid; n < NPRED; n += THREADS) {
        const float* p = pb + n * PRED_C;
        float p0 = p[0], p1 = p[1], p2 = p[2], p3 = p[3], p4 = p[4];
        float cx = (p0 * 2.f - 1.f) * 736.f;   // IMG_W/2
        float cy = (p1 * 2.f - 1.f) * 416.f;   // IMG_H/2
        float w  = expf(p2) * 32.f;            // 1472/46 == 32 exactly
        float h  = expf(p3) * 32.f;            // 832/26  == 32 exactly
        sbox[n]   = make_float4(cx - 0.5f * w, cy - 0.5f * h,
                                cx + 0.5f * w, cy + 0.5f * h);
        slogit[n] = p4;
        spos[n]   = 0.f;
        s_conf += fmaxf(p4, 0.f) + log1pf(expf(-fabsf(p4)));
    }
    if (tid < NTGT) {
        float4 tb = *reinterpret_cast<const float4*>(
            tbox + ((size_t)b * NTGT + tid) * 4);
        stgt[tid] = tb;
        float x1 = tb.x, y1 = tb.y, x2 = tb.z, y2 = tb.w;
        for (int off = 32; off > 0; off >>= 1) {
            x1 = fminf(x1, __shfl_xor(x1, off));
            y1 = fminf(y1, __shfl_xor(y1, off));
            x2 = fmaxf(x2, __shfl_xor(x2, off));
            y2 = fmaxf(y2, __shfl_xor(y2, off));
        }
        if (tid == 0) {
            shull[0] = x1; shull[1] = y1; shull[2] = x2; shull[3] = y2;
            stotal = 0;
        }
    }
    __syncthreads();

    // ---- Phase A2: cull boxes that miss the target hull (IoU==0 for all t),
    //      order-preserving ballot/prefix compaction ----
    {
        const float hx1 = shull[0], hy1 = shull[1];
        const float hx2 = shull[2], hy2 = shull[3];
        const int wv = tid >> 6, ln = tid & 63;
        for (int base = 0; base < NPRED; base += THREADS) {
            int n = base + tid;
            bool keep = false;
            float4 bb;
            if (n < NPRED) {
                bb = sbox[n];
                keep = (bb.x < hx2) & (bb.z > hx1) & (bb.y < hy2) & (bb.w > hy1);
            }
            unsigned long long m = __ballot(keep);
            if (ln == 0) swofs[wv] = __popcll(m);
            __syncthreads();
            if (tid == 0) {
                int run = stotal;
                for (int w = 0; w < NWAVE; ++w) {
                    int c = swofs[w]; swofs[w] = run; run += c;
                }
                stotal = run;
            }
            __syncthreads();
            if (keep) {
                int pos = swofs[wv] + __popcll(m & ((1ull << ln) - 1ull));
                cbox[pos]  = bb;
                carea[pos] = (bb.z - bb.x) * (bb.w - bb.y);
                cidx[pos]  = n;
            }
            __syncthreads();
        }
    }
    const int K = stotal;

    // ---- Phase B: per-target argmax of IoU over kept boxes, division-free ----
    {
        const int wv = tid >> 6, t = tid & 63;
        float4 tb = stgt[t];
        float a2 = (tb.z - tb.x) * (tb.w - tb.y);
        int lo = (wv * K) / NWAVE, hi = ((wv + 1) * K) / NWAVE;
        float binter = 0.f, buni = 1.f;
        int   bn = 0;                            // argmax of all-zeros == 0
        for (int j = lo; j < hi; ++j) {
            float4 bb = cbox[j];
            float a1  = carea[j];
            float ix1 = fmaxf(bb.x, tb.x);
            float iy1 = fmaxf(bb.y, tb.y);
            float ix2 = fminf(bb.z, tb.z);
            float iy2 = fminf(bb.w, tb.w);
            float iw  = fmaxf(ix2 - ix1, 0.f);
            float ih  = fmaxf(iy2 - iy1, 0.f);
            float inter = iw * ih;
            float uni   = (a1 + a2) - inter;
            bool better = inter * buni > binter * uni;  // strict: first-max wins
            binter = better ? inter : binter;
            buni   = better ? uni   : buni;
            bn     = better ? cidx[j] : bn;
        }
        sbint[tid] = binter; sbuni[tid] = buni; sbidx[tid] = bn;
    }
    __syncthreads();

    // ---- Phase C (lanes 0..63): combine waves, box + cls loss, pos mask ----
    float s_box = 0.f, s_cls = 0.f;
    if (tid < NTGT) {
        float binter = sbint[tid], buni = sbuni[tid];
        int   bn = sbidx[tid];
        for (int w = 1; w < NWAVE; ++w) {        // ascending: first-max wins
            float ci = sbint[w * 64 + tid];
            float cu = sbuni[w * 64 + tid];
            bool better = ci * buni > binter * cu;
            binter = better ? ci : binter;
            buni   = better ? cu : buni;
            bn     = better ? sbidx[w * 64 + tid] : bn;
        }
        int m = bn;
        spos[m] = 1.f;                           // set semantics; dup writes benign

        float4 pbx = sbox[m];
        float4 tb  = stgt[tid];
        float d;
        d = fabsf(pbx.x - tb.x); s_box += (d < 1.f) ? 0.5f * d * d : d - 0.5f;
        d = fabsf(pbx.y - tb.y); s_box += (d < 1.f) ? 0.5f * d * d : d - 0.5f;
        d = fabsf(pbx.z - tb.z); s_box += (d < 1.f) ? 0.5f * d * d : d - 0.5f;
        d = fabsf(pbx.w - tb.w); s_box += (d < 1.f) ? 0.5f * d * d : d - 0.5f;

        const float* pc = pb + m * PRED_C + 5;
        float x0 = pc[0], x1 = pc[1], x2 = pc[2], x3 = pc[3];
        float mx = fmaxf(fmaxf(x0, x1), fmaxf(x2, x3));
        float se = expf(x0 - mx) + expf(x1 - mx) + expf(x2 - mx) + expf(x3 - mx);
        float lse = mx + logf(se);
        int tc = tcls[(size_t)b * NTGT + tid];
        float xt = (tc == 0) ? x0 : (tc == 1) ? x1 : (tc == 2) ? x2 : x3;
        s_cls += lse - xt;
    }
    __syncthreads();

    // ---- Phase D: subtract matched conf logits (deduped via mask) ----
    float s_pos = 0.f;
    for (int n = tid; n < NPRED; n += THREADS)
        s_pos += spos[n] * slogit[n];

    // ---- block reduction of 5*box + cls + conf ----
    float v = s_conf - s_pos + 5.f * s_box + s_cls;
    for (int off = 32; off > 0; off >>= 1)
        v += __shfl_down(v, off);
    if ((tid & 63) == 0) sred[tid >> 6] = v;
    __syncthreads();
    if (tid == 0) {
        float t = 0.f;
        for (int i = 0; i < NWAVE; ++i) t += sred[i];
        partial[b] = t;
    }
}

__global__ __launch_bounds__(BATCH) void det_loss_final(
    const float* __restrict__ partial, float* __restrict__ out)
{
    int tid = threadIdx.x;
    float v = partial[tid];
    for (int off = 32; off > 0; off >>= 1)
        v += __shfl_down(v, off);
    __shared__ float s[8];
    if ((tid & 63) == 0) s[tid >> 6] = v;
    __syncthreads();
    if (tid == 0) {
        float t = 0.f;
        for (int i = 0; i < 8; ++i) t += s[i];
        *out = t * (1.f / BATCH);
    }
}

extern "C" void kernel_launch(void* const* d_in, const int* in_sizes, int n_in,
                              void* d_out, int out_size, void* d_ws, size_t ws_size,
                              hipStream_t stream) {
    const float* pred = (const float*)d_in[0];
    const float* tbox = (const float*)d_in[1];
    const int*   tcls = (const int*)d_in[2];
    float* out     = (float*)d_out;
    float* partial = (float*)d_ws;   // 512 floats, written every call

    det_loss_main<<<BATCH, THREADS, 0, stream>>>(pred, tbox, tcls, partial);
    det_loss_final<<<1, BATCH, 0, stream>>>(partial, out);
}